// Round 1
// baseline (162.103 us; speedup 1.0000x reference)
//
#include <hip/hip_runtime.h>
#include <math.h>

// Problem constants: x [N=64, D=768, H*W=L=576], conv_w [K=64, D=768], out [N, K*D]
#define EPSF 1e-12f

// ---------------------------------------------------------------------------
// Kernel A: per (n, 64-wide l-tile):
//   logits = W @ X_tile  (fp32 outer-product GEMM, W and X staged in LDS)
//   column norms of X accumulated during staging -> colinv
//   softmax over k per column, fold colinv -> att' written to ws
// ---------------------------------------------------------------------------
__global__ __launch_bounds__(128) void kA_gemm1_softmax(
    const float* __restrict__ x, const float* __restrict__ w,
    float* __restrict__ att) {
  __shared__ float Wl[64][65];   // [k][d] pad->no a-read conflicts; reused as att_s
  __shared__ float Xl[64][72];   // [d][l] pad 72 -> aligned float4 rows, 2-way max
  __shared__ float red[2][64];
  __shared__ float colinv[64];
  __shared__ float colmax[64];
  __shared__ float colscale[64];

  const int b = blockIdx.x;
  const int n = b / 9;
  const int l0 = (b % 9) * 64;
  const int t = threadIdx.x;
  const int lane = t & 63;  // l for loads
  const int half = t >> 6;  // 0..1
  const int kt = t >> 3;    // 0..15 -> k = kt*4+j
  const int ltr = t & 7;    // 0..7  -> l = ltr*8+i

  float c[4][8];
#pragma unroll
  for (int j = 0; j < 4; ++j)
#pragma unroll
    for (int i = 0; i < 8; ++i) c[j][i] = 0.f;
  float ssq = 0.f;

  const float* xb = x + (size_t)n * 768 * 576 + l0 + lane;

  for (int dc = 0; dc < 12; ++dc) {
    const int d0 = dc * 64;
    // stage W chunk [64k][64d] (coalesced: lane = d)
#pragma unroll
    for (int i = 0; i < 32; ++i) {
      const int k = half + 2 * i;
      Wl[k][lane] = w[k * 768 + d0 + lane];
    }
    // stage X chunk [64d][64l] (coalesced: lane = l) + accumulate column sumsq
#pragma unroll
    for (int i = 0; i < 32; ++i) {
      const int d = half + 2 * i;
      const float v = xb[(size_t)(d0 + d) * 576];
      Xl[d][lane] = v;
      ssq += v * v;
    }
    __syncthreads();
#pragma unroll 4
    for (int d = 0; d < 64; ++d) {
      float a[4], bb[8];
      *(float4*)&bb[0] = *(const float4*)&Xl[d][ltr * 8];
      *(float4*)&bb[4] = *(const float4*)&Xl[d][ltr * 8 + 4];
#pragma unroll
      for (int j = 0; j < 4; ++j) a[j] = Wl[kt * 4 + j][d];
#pragma unroll
      for (int j = 0; j < 4; ++j)
#pragma unroll
        for (int i = 0; i < 8; ++i) c[j][i] = fmaf(a[j], bb[i], c[j][i]);
    }
    __syncthreads();
  }

  // column inverse norms: invn = 1/max(||x_col||, eps)
  red[half][lane] = ssq;
  __syncthreads();
  if (t < 64) {
    const float ss = red[0][t] + red[1][t];
    colinv[t] = 1.f / fmaxf(sqrtf(ss), EPSF);
  }
  __syncthreads();

  // scaled logits into Wl (W no longer needed)
#pragma unroll
  for (int j = 0; j < 4; ++j)
#pragma unroll
    for (int i = 0; i < 8; ++i) {
      const int l = ltr * 8 + i;
      Wl[kt * 4 + j][l] = c[j][i] * colinv[l];
    }
  __syncthreads();

  // softmax over k per column l (each thread owns half a column)
  {
    float m = -1e30f;
#pragma unroll
    for (int i = 0; i < 32; ++i) m = fmaxf(m, Wl[half * 32 + i][lane]);
    red[half][lane] = m;
  }
  __syncthreads();
  if (t < 64) colmax[t] = fmaxf(red[0][t], red[1][t]);
  __syncthreads();
  {
    const float m = colmax[lane];
    float s = 0.f;
#pragma unroll
    for (int i = 0; i < 32; ++i) {
      const int k = half * 32 + i;
      const float e = expf(Wl[k][lane] - m);
      Wl[k][lane] = e;
      s += e;
    }
    red[half][lane] = s;
  }
  __syncthreads();
  // att' = exp/sum * colinv   (colinv folded so GEMM2 can read raw x)
  if (t < 64) colscale[t] = colinv[t] / (red[0][t] + red[1][t]);
  __syncthreads();
  {
    float* ab = att + (size_t)n * 64 * 576 + l0 + lane;
#pragma unroll
    for (int i = 0; i < 32; ++i) {
      const int k = half * 32 + i;
      ab[(size_t)k * 576] = Wl[k][lane] * colscale[lane];
    }
  }
}

// ---------------------------------------------------------------------------
// Kernel B: per (n, 64-wide d-tile): out[k][d] = sum_l att'[k][l] * x[d][l]
// LDS chunks transposed to [l][k] / [l][d] so inner loop reads are float4.
// ---------------------------------------------------------------------------
__global__ __launch_bounds__(128) void kB_gemm2(
    const float* __restrict__ x, const float* __restrict__ att,
    float* __restrict__ out) {
  __shared__ float attT[32][68];  // [l][k]
  __shared__ float xT[32][68];    // [l][d]

  const int b = blockIdx.x;
  const int n = b / 12;
  const int d0 = (b % 12) * 64;
  const int t = threadIdx.x;
  const int l = t & 31;
  const int grp = t >> 5;  // 0..3
  const int kt = t >> 3;   // 0..15 -> k = kt*4+j
  const int dt = t & 7;    // 0..7  -> d = dt*8+i

  float c[4][8];
#pragma unroll
  for (int j = 0; j < 4; ++j)
#pragma unroll
    for (int i = 0; i < 8; ++i) c[j][i] = 0.f;

  const float* ab = att + (size_t)n * 64 * 576 + l;
  const float* xb = x + ((size_t)n * 768 + d0) * 576 + l;

  for (int lc = 0; lc < 18; ++lc) {
    const int lo = lc * 32;
#pragma unroll
    for (int i = 0; i < 16; ++i) {
      const int k = grp + 4 * i;
      attT[l][k] = ab[(size_t)k * 576 + lo];
    }
#pragma unroll
    for (int i = 0; i < 16; ++i) {
      const int d = grp + 4 * i;
      xT[l][d] = xb[(size_t)d * 576 + lo];
    }
    __syncthreads();
#pragma unroll 4
    for (int ll = 0; ll < 32; ++ll) {
      float a[4], bb[8];
      *(float4*)&a[0] = *(const float4*)&attT[ll][kt * 4];
      *(float4*)&bb[0] = *(const float4*)&xT[ll][dt * 8];
      *(float4*)&bb[4] = *(const float4*)&xT[ll][dt * 8 + 4];
#pragma unroll
      for (int j = 0; j < 4; ++j)
#pragma unroll
        for (int i = 0; i < 8; ++i) c[j][i] = fmaf(a[j], bb[i], c[j][i]);
    }
    __syncthreads();
  }

  // store raw out (normalized by kernels C1-C3 in place)
  float* ob = out + (size_t)n * 64 * 768 + d0;
#pragma unroll
  for (int j = 0; j < 4; ++j) {
    float4 v0 = make_float4(c[j][0], c[j][1], c[j][2], c[j][3]);
    float4 v1 = make_float4(c[j][4], c[j][5], c[j][6], c[j][7]);
    float* row = ob + (size_t)(kt * 4 + j) * 768 + dt * 8;
    *(float4*)row = v0;
    *(float4*)(row + 4) = v1;
  }
}

// ---------------------------------------------------------------------------
// Epilogue: per-(n,k) sumsq -> per-n scales -> in-place scale of d_out
// ---------------------------------------------------------------------------
__global__ __launch_bounds__(64) void kC1_rowssq(const float* __restrict__ out,
                                                 float* __restrict__ ssq) {
  const int b = blockIdx.x;  // n*64 + k
  const int t = threadIdx.x;
  const float* p = out + (size_t)b * 768;
  float s = 0.f;
#pragma unroll
  for (int i = 0; i < 12; ++i) {
    const float v = p[t + 64 * i];
    s = fmaf(v, v, s);
  }
#pragma unroll
  for (int off = 32; off >= 1; off >>= 1) s += __shfl_xor(s, off, 64);
  if (t == 0) ssq[b] = s;
}

__global__ __launch_bounds__(64) void kC2_scales(const float* __restrict__ ssq,
                                                 float* __restrict__ scale) {
  const int n = blockIdx.x;
  const int t = threadIdx.x;  // = k
  const float ss = ssq[n * 64 + t];
  const float invk = 1.f / fmaxf(sqrtf(ss), EPSF);
  float r = ss * invk * invk;  // normalized-row sumsq (~1)
#pragma unroll
  for (int off = 32; off >= 1; off >>= 1) r += __shfl_xor(r, off, 64);
  const float ginv = 1.f / fmaxf(sqrtf(r), EPSF);
  scale[n * 64 + t] = invk * ginv;
}

__global__ __launch_bounds__(256) void kC3_apply(float* __restrict__ out,
                                                 const float* __restrict__ scale) {
  const int i = blockIdx.x * 256 + threadIdx.x;  // over float4s, exactly covers
  const int row = i / 192;                       // 768/4 float4 per (n,k) row
  const float s = scale[row];
  float4 v = ((float4*)out)[i];
  v.x *= s; v.y *= s; v.z *= s; v.w *= s;
  ((float4*)out)[i] = v;
}

// ---------------------------------------------------------------------------
extern "C" void kernel_launch(void* const* d_in, const int* in_sizes, int n_in,
                              void* d_out, int out_size, void* d_ws, size_t ws_size,
                              hipStream_t stream) {
  const float* x = (const float*)d_in[0];   // [64,768,24,24]
  const float* w = (const float*)d_in[1];   // [64,768]
  float* out = (float*)d_out;               // [64, 64*768]

  float* att = (float*)d_ws;                // [64,64,576] = 9.44 MB
  float* ssq = att + (size_t)64 * 64 * 576; // [4096]
  float* scale = ssq + 4096;                // [4096]

  kA_gemm1_softmax<<<576, 128, 0, stream>>>(x, w, att);
  kB_gemm2<<<768, 128, 0, stream>>>(x, att, out);
  kC1_rowssq<<<4096, 64, 0, stream>>>(out, ssq);
  kC2_scales<<<64, 64, 0, stream>>>(ssq, scale);
  kC3_apply<<<3072, 256, 0, stream>>>(out, scale);
}

// Round 3
// 117.454 us; speedup vs baseline: 1.3801x; 1.3801x over previous
//
#include <hip/hip_runtime.h>
#include <math.h>

#define EPSF 1e-12f
#define DD 768
#define LL 576

typedef unsigned short u16;
typedef __attribute__((ext_vector_type(8))) short bf16x8;
typedef __attribute__((ext_vector_type(4))) float f32x4;

__device__ __forceinline__ u16 bf16h(float v) {
  unsigned u = __float_as_uint(v);
  return (u16)((u + 0x7FFFu + ((u >> 16) & 1u)) >> 16);
}

// split 8 floats -> packed hi uint4, lo uint4 (bf16 RNE, lo = v - hi)
__device__ __forceinline__ void split8(const float* v, uint4& ph, uint4& pl) {
  unsigned h[8], lo[8];
#pragma unroll
  for (int i = 0; i < 8; ++i) {
    unsigned u = __float_as_uint(v[i]);
    unsigned r = (u + 0x7FFFu + ((u >> 16) & 1u)) >> 16;
    h[i] = r;
    float rest = v[i] - __uint_as_float(r << 16);
    unsigned u2 = __float_as_uint(rest);
    lo[i] = (u2 + 0x7FFFu + ((u2 >> 16) & 1u)) >> 16;
  }
  ph = make_uint4(h[0] | (h[1] << 16), h[2] | (h[3] << 16),
                  h[4] | (h[5] << 16), h[6] | (h[7] << 16));
  pl = make_uint4(lo[0] | (lo[1] << 16), lo[2] | (lo[3] << 16),
                  lo[4] | (lo[5] << 16), lo[6] | (lo[7] << 16));
}

// Layout probe: D1 = (bcast m-label) x (ones) -> 32*row ; D2 = (ones) x
// (bcast n-label) -> 32*col. Gives each acc reg's TRUE (row,col) under any
// D-layout / operand-order convention. Exact integer arithmetic in bf16.
__device__ __forceinline__ void probe_layout(int lane, int* rowz, int* colz) {
  bf16x8 va, v1;
  const short ml = (short)bf16h((float)(lane & 15));
  const short on = (short)0x3F80;  // bf16(1.0)
#pragma unroll
  for (int e = 0; e < 8; ++e) { va[e] = ml; v1[e] = on; }
  f32x4 z = {0.f, 0.f, 0.f, 0.f};
  f32x4 D1 = __builtin_amdgcn_mfma_f32_16x16x32_bf16(va, v1, z, 0, 0, 0);
  f32x4 D2 = __builtin_amdgcn_mfma_f32_16x16x32_bf16(v1, va, z, 0, 0, 0);
#pragma unroll
  for (int r = 0; r < 4; ++r) {
    rowz[r] = (int)(D1[r] * 0.03125f + 0.5f);
    colz[r] = (int)(D2[r] * 0.03125f + 0.5f);
  }
}

// ---------------------------------------------------------------------------
// kA: per (n, 64-l tile): logits = W @ X via split-bf16 MFMA. Plain fp32 LDS
// tiles, fragments assembled in-register (no transpose phase, no swizzle).
// colinv from staged X; softmax over k; fold colinv; att' as bf16 hi/lo.
// ---------------------------------------------------------------------------
__global__ __launch_bounds__(256) void kA(const float* __restrict__ x,
                                          const float* __restrict__ w,
                                          u16* __restrict__ attH,
                                          u16* __restrict__ attL) {
  __shared__ __align__(16) float Ws[64][36];   // W chunk [k][32d]
  __shared__ __align__(16) float raw[32][68];  // X chunk [32d][64l]
  __shared__ __align__(16) float Ls[64][68];   // logits [k][l]
  __shared__ float red[4][64];
  __shared__ float colinv[64], colmax[64], colscale[64];

  const int b = blockIdx.x;
  const int n = b / 9, l0 = (b % 9) * 64;
  const int t = threadIdx.x;
  const int wv = t >> 6, lane = t & 63;

  int rowz[4], colz[4];
  probe_layout(lane, rowz, colz);

  f32x4 z = {0.f, 0.f, 0.f, 0.f};
  f32x4 acc[4] = {z, z, z, z};
  float ssq4[4] = {0.f, 0.f, 0.f, 0.f};

  const int xd = t >> 4;        // 0..15 (+16 on j=1)
  const int xl = (t & 15) * 4;  // l quad
  const int wk = t >> 2;        // 0..63
  const int wd = (t & 3) * 8;   // 0,8,16,24

  const float* xbase = x + (size_t)n * DD * LL + l0;

  for (int s = 0; s < 24; ++s) {
    const int d0 = s * 32;
    __syncthreads();  // protect previous step's LDS reads
    // W chunk [64k][32d] fp32
    {
      const float* g = w + wk * DD + d0 + wd;
      *(float4*)&Ws[wk][wd] = *(const float4*)g;
      *(float4*)&Ws[wk][wd + 4] = *(const float4*)(g + 4);
    }
    // X chunk [32d][64l] fp32 + column sumsq
#pragma unroll
    for (int j = 0; j < 2; ++j) {
      const int d = xd + 16 * j;
      float4 v = *(const float4*)(xbase + (size_t)(d0 + d) * LL + xl);
      *(float4*)&raw[d][xl] = v;
      ssq4[0] = fmaf(v.x, v.x, ssq4[0]);
      ssq4[1] = fmaf(v.y, v.y, ssq4[1]);
      ssq4[2] = fmaf(v.z, v.z, ssq4[2]);
      ssq4[3] = fmaf(v.w, v.w, ssq4[3]);
    }
    __syncthreads();
    // fragments in-register + MFMA
    {
      const int g8 = (lane >> 4) * 8;
      const int ar = wv * 16 + (lane & 15);
      float av[8];
      *(float4*)&av[0] = *(const float4*)&Ws[ar][g8];
      *(float4*)&av[4] = *(const float4*)&Ws[ar][g8 + 4];
      uint4 ph, pl;
      split8(av, ph, pl);
      bf16x8 Ah = *(bf16x8*)&ph;
      bf16x8 Alo = *(bf16x8*)&pl;
#pragma unroll
      for (int lt = 0; lt < 4; ++lt) {
        const int bl = lt * 16 + (lane & 15);
        float bv[8];
#pragma unroll
        for (int j = 0; j < 8; ++j) bv[j] = raw[g8 + j][bl];
        uint4 qh, ql;
        split8(bv, qh, ql);
        bf16x8 Bh = *(bf16x8*)&qh;
        bf16x8 Bl = *(bf16x8*)&ql;
        acc[lt] = __builtin_amdgcn_mfma_f32_16x16x32_bf16(Ah, Bh, acc[lt], 0, 0, 0);
        acc[lt] = __builtin_amdgcn_mfma_f32_16x16x32_bf16(Ah, Bl, acc[lt], 0, 0, 0);
        acc[lt] = __builtin_amdgcn_mfma_f32_16x16x32_bf16(Alo, Bh, acc[lt], 0, 0, 0);
      }
    }
  }

  // column sumsq reduce: partners are lane^16, lane^32 (same lane&15)
#pragma unroll
  for (int i = 0; i < 4; ++i) {
    ssq4[i] += __shfl_xor(ssq4[i], 16, 64);
    ssq4[i] += __shfl_xor(ssq4[i], 32, 64);
  }
  if (lane < 16) {
#pragma unroll
    for (int i = 0; i < 4; ++i) red[wv][lane * 4 + i] = ssq4[i];
  }
  __syncthreads();
  if (t < 64) {
    const float ss = red[0][t] + red[1][t] + red[2][t] + red[3][t];
    colinv[t] = 1.f / fmaxf(sqrtf(ss), EPSF);
  }
  __syncthreads();
  // scatter raw logits using PROBED positions
#pragma unroll
  for (int lt = 0; lt < 4; ++lt)
#pragma unroll
    for (int r = 0; r < 4; ++r)
      Ls[wv * 16 + rowz[r]][lt * 16 + colz[r]] = acc[lt][r];
  __syncthreads();

  // softmax over k per column; thread (q=t>>6, cl=t&63) owns 16 k's
  const int cl = t & 63, q = t >> 6;
  const float cinv = colinv[cl];
  float v[16];
  float m = -1e30f;
#pragma unroll
  for (int i = 0; i < 16; ++i) {
    const float vv = Ls[q * 16 + i][cl] * cinv;
    v[i] = vv;
    m = fmaxf(m, vv);
  }
  red[q][cl] = m;
  __syncthreads();
  if (t < 64) colmax[t] = fmaxf(fmaxf(red[0][t], red[1][t]), fmaxf(red[2][t], red[3][t]));
  __syncthreads();
  const float M = colmax[cl];
  float ssum = 0.f;
#pragma unroll
  for (int i = 0; i < 16; ++i) {
    const float e = expf(v[i] - M);
    v[i] = e;
    ssum += e;
  }
  red[q][cl] = ssum;
  __syncthreads();
  if (t < 64) colscale[t] = colinv[t] / (red[0][t] + red[1][t] + red[2][t] + red[3][t]);
  __syncthreads();
  const float cs = colscale[cl];
  u16* aH = attH + ((size_t)n * 64) * LL + l0 + cl;
  u16* aL = attL + ((size_t)n * 64) * LL + l0 + cl;
#pragma unroll
  for (int i = 0; i < 16; ++i) {
    const int k = q * 16 + i;
    const float e = v[i] * cs;
    unsigned u = __float_as_uint(e);
    unsigned r = (u + 0x7FFFu + ((u >> 16) & 1u)) >> 16;
    const float rest = e - __uint_as_float(r << 16);
    aH[(size_t)k * LL] = (u16)r;
    aL[(size_t)k * LL] = bf16h(rest);
  }
}

// ---------------------------------------------------------------------------
// kB: per (n, 64-d tile): out[k][d] = sum_l att'[k][l] * x[d][l], split-bf16
// MFMA. Both operands l-contiguous; output positions from probe.
// ---------------------------------------------------------------------------
__global__ __launch_bounds__(256) void kB(const float* __restrict__ x,
                                          const u16* __restrict__ attH,
                                          const u16* __restrict__ attL,
                                          float* __restrict__ out) {
  __shared__ __align__(16) u16 AH[64][40];
  __shared__ __align__(16) u16 AL[64][40];
  __shared__ __align__(16) u16 Xh[64][40];
  __shared__ __align__(16) u16 Xl[64][40];
  const int b = blockIdx.x;
  const int n = b / 12, d0 = (b % 12) * 64;
  const int t = threadIdx.x;
  const int wv = t >> 6, lane = t & 63;

  int rowz[4], colz[4];
  probe_layout(lane, rowz, colz);

  f32x4 z = {0.f, 0.f, 0.f, 0.f};
  f32x4 acc[4] = {z, z, z, z};

  const int rk = t >> 2;       // staging row 0..63
  const int lb = (t & 3) * 8;  // l offset 0,8,16,24

  const u16* aHb = attH + ((size_t)n * 64 + rk) * LL + lb;
  const u16* aLb = attL + ((size_t)n * 64 + rk) * LL + lb;
  const float* xb = x + ((size_t)n * DD + d0 + rk) * LL + lb;

  for (int s = 0; s < 18; ++s) {
    const int l0 = s * 32;
    __syncthreads();
    *(uint4*)&AH[rk][lb] = *(const uint4*)(aHb + l0);
    *(uint4*)&AL[rk][lb] = *(const uint4*)(aLb + l0);
    {
      float4 a = *(const float4*)(xb + l0);
      float4 c = *(const float4*)(xb + l0 + 4);
      float v[8] = {a.x, a.y, a.z, a.w, c.x, c.y, c.z, c.w};
      uint4 ph, pl;
      split8(v, ph, pl);
      *(uint4*)&Xh[rk][lb] = ph;
      *(uint4*)&Xl[rk][lb] = pl;
    }
    __syncthreads();
    const int ar = wv * 16 + (lane & 15);
    const int ab = (lane >> 4) * 8;
    bf16x8 Ah = *(const bf16x8*)&AH[ar][ab];
    bf16x8 Alo = *(const bf16x8*)&AL[ar][ab];
#pragma unroll
    for (int dt = 0; dt < 4; ++dt) {
      const int br = dt * 16 + (lane & 15);
      bf16x8 Bh = *(const bf16x8*)&Xh[br][ab];
      bf16x8 Bl = *(const bf16x8*)&Xl[br][ab];
      acc[dt] = __builtin_amdgcn_mfma_f32_16x16x32_bf16(Ah, Bh, acc[dt], 0, 0, 0);
      acc[dt] = __builtin_amdgcn_mfma_f32_16x16x32_bf16(Ah, Bl, acc[dt], 0, 0, 0);
      acc[dt] = __builtin_amdgcn_mfma_f32_16x16x32_bf16(Alo, Bh, acc[dt], 0, 0, 0);
    }
  }

  // store raw out using PROBED positions
  float* ob = out + ((size_t)n * 64 + wv * 16) * DD + d0;
#pragma unroll
  for (int dt = 0; dt < 4; ++dt)
#pragma unroll
    for (int r = 0; r < 4; ++r)
      ob[(size_t)rowz[r] * DD + dt * 16 + colz[r]] = acc[dt][r];
}

// ---------------------------------------------------------------------------
// Epilogue (round-1 verified versions)
// ---------------------------------------------------------------------------
__global__ __launch_bounds__(64) void kC1(const float* __restrict__ out,
                                          float* __restrict__ ssq) {
  const int b = blockIdx.x;  // n*64 + k
  const int t = threadIdx.x;
  const float* p = out + (size_t)b * DD;
  float s = 0.f;
#pragma unroll
  for (int i = 0; i < 12; ++i) {
    const float v = p[t + 64 * i];
    s = fmaf(v, v, s);
  }
#pragma unroll
  for (int off = 32; off >= 1; off >>= 1) s += __shfl_xor(s, off, 64);
  if (t == 0) ssq[b] = s;
}

__global__ __launch_bounds__(64) void kC2(const float* __restrict__ ssq,
                                          float* __restrict__ scale) {
  const int n = blockIdx.x;
  const int t = threadIdx.x;  // = k
  const float ss = ssq[n * 64 + t];
  const float invk = 1.f / fmaxf(sqrtf(ss), EPSF);
  float r = ss * invk * invk;
#pragma unroll
  for (int off = 32; off >= 1; off >>= 1) r += __shfl_xor(r, off, 64);
  const float ginv = 1.f / fmaxf(sqrtf(r), EPSF);
  scale[n * 64 + t] = invk * ginv;
}

__global__ __launch_bounds__(256) void kC3(float* __restrict__ out,
                                           const float* __restrict__ scale) {
  const int i = blockIdx.x * 256 + threadIdx.x;
  const int row = i / 192;
  const float s = scale[row];
  float4 v = ((float4*)out)[i];
  v.x *= s; v.y *= s; v.z *= s; v.w *= s;
  ((float4*)out)[i] = v;
}

// ---------------------------------------------------------------------------
extern "C" void kernel_launch(void* const* d_in, const int* in_sizes, int n_in,
                              void* d_out, int out_size, void* d_ws, size_t ws_size,
                              hipStream_t stream) {
  const float* x = (const float*)d_in[0];  // [64,768,24,24]
  const float* w = (const float*)d_in[1];  // [64,768]
  float* out = (float*)d_out;              // [64, 64*768]

  u16* attH = (u16*)d_ws;                               // [64,64,576] bf16 hi
  u16* attL = attH + (size_t)64 * 64 * 576;             // lo plane
  float* ssq = (float*)(attL + (size_t)64 * 64 * 576);  // [4096]
  float* scale = ssq + 4096;                            // [4096]

  kA<<<576, 256, 0, stream>>>(x, w, attH, attL);
  kB<<<768, 256, 0, stream>>>(x, attH, attL, out);
  kC1<<<4096, 64, 0, stream>>>(out, ssq);
  kC2<<<64, 64, 0, stream>>>(ssq, scale);
  kC3<<<3072, 256, 0, stream>>>(out, scale);
}

// Round 4
// 93.436 us; speedup vs baseline: 1.7349x; 1.2570x over previous
//
#include <hip/hip_runtime.h>
#include <math.h>

#define EPSF 1e-12f
#define DD 768
#define LL 576

typedef unsigned short u16;
typedef __attribute__((ext_vector_type(8))) short bf16x8;
typedef __attribute__((ext_vector_type(4))) float f32x4;

__device__ __forceinline__ u16 bf16h(float v) {
  unsigned u = __float_as_uint(v);
  return (u16)((u + 0x7FFFu + ((u >> 16) & 1u)) >> 16);
}

// split 8 floats -> packed hi uint4, lo uint4 (bf16 RNE, lo = v - hi)
__device__ __forceinline__ void split8(const float* v, uint4& ph, uint4& pl) {
  unsigned h[8], lo[8];
#pragma unroll
  for (int i = 0; i < 8; ++i) {
    unsigned u = __float_as_uint(v[i]);
    unsigned r = (u + 0x7FFFu + ((u >> 16) & 1u)) >> 16;
    h[i] = r;
    float rest = v[i] - __uint_as_float(r << 16);
    unsigned u2 = __float_as_uint(rest);
    lo[i] = (u2 + 0x7FFFu + ((u2 >> 16) & 1u)) >> 16;
  }
  ph = make_uint4(h[0] | (h[1] << 16), h[2] | (h[3] << 16),
                  h[4] | (h[5] << 16), h[6] | (h[7] << 16));
  pl = make_uint4(lo[0] | (lo[1] << 16), lo[2] | (lo[3] << 16),
                  lo[4] | (lo[5] << 16), lo[6] | (lo[7] << 16));
}

// Layout probe: D1 = (bcast m-label) x (ones) -> 32*row ; D2 = (ones) x
// (bcast n-label) -> 32*col. Gives each acc reg's TRUE (row,col) under any
// D-layout / operand-order convention. Exact integer arithmetic in bf16.
__device__ __forceinline__ void probe_layout(int lane, int* rowz, int* colz) {
  bf16x8 va, v1;
  const short ml = (short)bf16h((float)(lane & 15));
  const short on = (short)0x3F80;  // bf16(1.0)
#pragma unroll
  for (int e = 0; e < 8; ++e) { va[e] = ml; v1[e] = on; }
  f32x4 z = {0.f, 0.f, 0.f, 0.f};
  f32x4 D1 = __builtin_amdgcn_mfma_f32_16x16x32_bf16(va, v1, z, 0, 0, 0);
  f32x4 D2 = __builtin_amdgcn_mfma_f32_16x16x32_bf16(v1, va, z, 0, 0, 0);
#pragma unroll
  for (int r = 0; r < 4; ++r) {
    rowz[r] = (int)(D1[r] * 0.03125f + 0.5f);
    colz[r] = (int)(D2[r] * 0.03125f + 0.5f);
  }
}

// ---------------------------------------------------------------------------
// kA: per (n, 64-l tile): logits = W @ X via split-bf16 MFMA.
// Block-cooperative transpose+split of X ONCE per step (XOR block swizzle,
// conflict-free); MFMA phase reads only b128 rows. Probe-based scatter.
// ---------------------------------------------------------------------------
__global__ __launch_bounds__(256) void kA(const float* __restrict__ x,
                                          const float* __restrict__ w,
                                          u16* __restrict__ attH,
                                          u16* __restrict__ attL) {
  __shared__ __align__(16) char pool[29184];
  float (*raw)[68] = (float(*)[68])pool;        // [32d][64l] fp32, 8704B
  u16 (*Wh)[40] = (u16(*)[40])(pool + 8704);    // [64k][32d]+pad
  u16 (*Wl)[40] = (u16(*)[40])(pool + 13824);
  u16 (*Xh)[40] = (u16(*)[40])(pool + 18944);   // [64l][32d swizzled]+pad
  u16 (*Xl)[40] = (u16(*)[40])(pool + 24064);
  float (*Ls)[68] = (float(*)[68])pool;         // [64k][64l] aliases pool
  __shared__ float red[4][64];
  __shared__ float colinv[64], colmax[64], colscale[64];

  const int b = blockIdx.x;
  const int n = b / 9, l0 = (b % 9) * 64;
  const int t = threadIdx.x;
  const int wv = t >> 6, lane = t & 63;

  int rowz[4], colz[4];
  probe_layout(lane, rowz, colz);

  f32x4 z = {0.f, 0.f, 0.f, 0.f};
  f32x4 acc[4] = {z, z, z, z};
  float ssq4[4] = {0.f, 0.f, 0.f, 0.f};

  const int xd = t >> 4;        // 0..15 (+16 on j=1)
  const int xl = (t & 15) * 4;  // l quad
  const int wk = t >> 2;        // 0..63
  const int wd = (t & 3) * 8;   // 0,8,16,24

  const float* xbase = x + (size_t)n * DD * LL + l0;

  for (int s = 0; s < 24; ++s) {
    const int d0 = s * 32;
    __syncthreads();  // prev step's LDS reads done
    // W chunk [64k][32d] -> split -> Wh/Wl (d-contiguous, no transpose)
    {
      const float* g = w + wk * DD + d0 + wd;
      float v[8];
      *(float4*)&v[0] = *(const float4*)g;
      *(float4*)&v[4] = *(const float4*)(g + 4);
      uint4 ph, pl;
      split8(v, ph, pl);
      *(uint4*)&Wh[wk][wd] = ph;
      *(uint4*)&Wl[wk][wd] = pl;
    }
    // X chunk [32d][64l] fp32 -> raw (+ column sumsq)
#pragma unroll
    for (int j = 0; j < 2; ++j) {
      const int d = xd + 16 * j;
      float4 v = *(const float4*)(xbase + (size_t)(d0 + d) * LL + xl);
      *(float4*)&raw[d][xl] = v;
      ssq4[0] = fmaf(v.x, v.x, ssq4[0]);
      ssq4[1] = fmaf(v.y, v.y, ssq4[1]);
      ssq4[2] = fmaf(v.z, v.z, ssq4[2]);
      ssq4[3] = fmaf(v.w, v.w, ssq4[3]);
    }
    __syncthreads();
    // block-wide transpose+split ONCE: raw[d][l] -> Xh/Xl[l][d-swizzled]
    {
      const int tl = lane;  // row l (lane = fastest dim -> conflict-free reads)
      const int dg = wv;    // d block 0..3
      float v[8];
#pragma unroll
      for (int j = 0; j < 8; ++j) v[j] = raw[dg * 8 + j][tl];
      uint4 ph, pl;
      split8(v, ph, pl);
      const int pb = (dg ^ ((tl >> 3) & 3)) * 8;
      *(uint4*)&Xh[tl][pb] = ph;
      *(uint4*)&Xl[tl][pb] = pl;
    }
    __syncthreads();
    // MFMA phase: pure b128 row reads (swizzle -> 4 groups hit 4 slots)
    {
      const int ar = wv * 16 + (lane & 15);
      const int g8 = (lane >> 4) * 8;
      bf16x8 Ah = *(const bf16x8*)&Wh[ar][g8];
      bf16x8 Alo = *(const bf16x8*)&Wl[ar][g8];
#pragma unroll
      for (int lt = 0; lt < 4; ++lt) {
        const int bl = lt * 16 + (lane & 15);
        const int pb = ((lane >> 4) ^ ((bl >> 3) & 3)) * 8;
        bf16x8 Bh = *(const bf16x8*)&Xh[bl][pb];
        bf16x8 Bl = *(const bf16x8*)&Xl[bl][pb];
        acc[lt] = __builtin_amdgcn_mfma_f32_16x16x32_bf16(Ah, Bh, acc[lt], 0, 0, 0);
        acc[lt] = __builtin_amdgcn_mfma_f32_16x16x32_bf16(Ah, Bl, acc[lt], 0, 0, 0);
        acc[lt] = __builtin_amdgcn_mfma_f32_16x16x32_bf16(Alo, Bh, acc[lt], 0, 0, 0);
      }
    }
  }

  // column sumsq reduce: partners lane^16, lane^32 (same lane&15)
#pragma unroll
  for (int i = 0; i < 4; ++i) {
    ssq4[i] += __shfl_xor(ssq4[i], 16, 64);
    ssq4[i] += __shfl_xor(ssq4[i], 32, 64);
  }
  if (lane < 16) {
#pragma unroll
    for (int i = 0; i < 4; ++i) red[wv][lane * 4 + i] = ssq4[i];
  }
  __syncthreads();
  if (t < 64) {
    const float ss = red[0][t] + red[1][t] + red[2][t] + red[3][t];
    colinv[t] = 1.f / fmaxf(sqrtf(ss), EPSF);
  }
  __syncthreads();
  // scatter raw logits using PROBED positions (Ls aliases dead staging pool)
#pragma unroll
  for (int lt = 0; lt < 4; ++lt)
#pragma unroll
    for (int r = 0; r < 4; ++r)
      Ls[wv * 16 + rowz[r]][lt * 16 + colz[r]] = acc[lt][r];
  __syncthreads();

  // softmax over k per column; thread (q=t>>6, cl=t&63) owns 16 k's
  const int cl = t & 63, q = t >> 6;
  const float cinv = colinv[cl];
  float v[16];
  float m = -1e30f;
#pragma unroll
  for (int i = 0; i < 16; ++i) {
    const float vv = Ls[q * 16 + i][cl] * cinv;
    v[i] = vv;
    m = fmaxf(m, vv);
  }
  red[q][cl] = m;
  __syncthreads();
  if (t < 64) colmax[t] = fmaxf(fmaxf(red[0][t], red[1][t]), fmaxf(red[2][t], red[3][t]));
  __syncthreads();
  const float M = colmax[cl];
  float ssum = 0.f;
#pragma unroll
  for (int i = 0; i < 16; ++i) {
    const float e = expf(v[i] - M);
    v[i] = e;
    ssum += e;
  }
  red[q][cl] = ssum;
  __syncthreads();
  if (t < 64) colscale[t] = colinv[t] / (red[0][t] + red[1][t] + red[2][t] + red[3][t]);
  __syncthreads();
  const float cs = colscale[cl];
  u16* aH = attH + ((size_t)n * 64) * LL + l0 + cl;
  u16* aL = attL + ((size_t)n * 64) * LL + l0 + cl;
#pragma unroll
  for (int i = 0; i < 16; ++i) {
    const int k = q * 16 + i;
    const float e = v[i] * cs;
    unsigned u = __float_as_uint(e);
    unsigned r = (u + 0x7FFFu + ((u >> 16) & 1u)) >> 16;
    const float rest = e - __uint_as_float(r << 16);
    aH[(size_t)k * LL] = (u16)r;
    aL[(size_t)k * LL] = bf16h(rest);
  }
}

// ---------------------------------------------------------------------------
// kB: per (n, 64-d tile): out[k][d] = sum_l att'[k][l] * x[d][l], split-bf16
// MFMA. Both operands l-contiguous; output positions from probe.
// ---------------------------------------------------------------------------
__global__ __launch_bounds__(256) void kB(const float* __restrict__ x,
                                          const u16* __restrict__ attH,
                                          const u16* __restrict__ attL,
                                          float* __restrict__ out) {
  __shared__ __align__(16) u16 AH[64][40];
  __shared__ __align__(16) u16 AL[64][40];
  __shared__ __align__(16) u16 Xh[64][40];
  __shared__ __align__(16) u16 Xl[64][40];
  const int b = blockIdx.x;
  const int n = b / 12, d0 = (b % 12) * 64;
  const int t = threadIdx.x;
  const int wv = t >> 6, lane = t & 63;

  int rowz[4], colz[4];
  probe_layout(lane, rowz, colz);

  f32x4 z = {0.f, 0.f, 0.f, 0.f};
  f32x4 acc[4] = {z, z, z, z};

  const int rk = t >> 2;       // staging row 0..63
  const int lb = (t & 3) * 8;  // l offset 0,8,16,24

  const u16* aHb = attH + ((size_t)n * 64 + rk) * LL + lb;
  const u16* aLb = attL + ((size_t)n * 64 + rk) * LL + lb;
  const float* xb = x + ((size_t)n * DD + d0 + rk) * LL + lb;

  for (int s = 0; s < 18; ++s) {
    const int l0 = s * 32;
    __syncthreads();
    *(uint4*)&AH[rk][lb] = *(const uint4*)(aHb + l0);
    *(uint4*)&AL[rk][lb] = *(const uint4*)(aLb + l0);
    {
      float v[8];
      *(float4*)&v[0] = *(const float4*)(xb + l0);
      *(float4*)&v[4] = *(const float4*)(xb + l0 + 4);
      uint4 ph, pl;
      split8(v, ph, pl);
      *(uint4*)&Xh[rk][lb] = ph;
      *(uint4*)&Xl[rk][lb] = pl;
    }
    __syncthreads();
    const int ar = wv * 16 + (lane & 15);
    const int ab = (lane >> 4) * 8;
    bf16x8 Ah = *(const bf16x8*)&AH[ar][ab];
    bf16x8 Alo = *(const bf16x8*)&AL[ar][ab];
#pragma unroll
    for (int dt = 0; dt < 4; ++dt) {
      const int br = dt * 16 + (lane & 15);
      bf16x8 Bh = *(const bf16x8*)&Xh[br][ab];
      bf16x8 Bl = *(const bf16x8*)&Xl[br][ab];
      acc[dt] = __builtin_amdgcn_mfma_f32_16x16x32_bf16(Ah, Bh, acc[dt], 0, 0, 0);
      acc[dt] = __builtin_amdgcn_mfma_f32_16x16x32_bf16(Ah, Bl, acc[dt], 0, 0, 0);
      acc[dt] = __builtin_amdgcn_mfma_f32_16x16x32_bf16(Alo, Bh, acc[dt], 0, 0, 0);
    }
  }

  // store raw out using PROBED positions
  float* ob = out + ((size_t)n * 64 + wv * 16) * DD + d0;
#pragma unroll
  for (int dt = 0; dt < 4; ++dt)
#pragma unroll
    for (int r = 0; r < 4; ++r)
      ob[(size_t)rowz[r] * DD + dt * 16 + colz[r]] = acc[dt][r];
}

// ---------------------------------------------------------------------------
// Epilogue
// ---------------------------------------------------------------------------
__global__ __launch_bounds__(64) void kC1(const float* __restrict__ out,
                                          float* __restrict__ ssq) {
  const int b = blockIdx.x;  // n*64 + k
  const int t = threadIdx.x;
  const float* p = out + (size_t)b * DD;
  float s = 0.f;
#pragma unroll
  for (int i = 0; i < 12; ++i) {
    const float v = p[t + 64 * i];
    s = fmaf(v, v, s);
  }
#pragma unroll
  for (int off = 32; off >= 1; off >>= 1) s += __shfl_xor(s, off, 64);
  if (t == 0) ssq[b] = s;
}

__global__ __launch_bounds__(64) void kC2(const float* __restrict__ ssq,
                                          float* __restrict__ scale) {
  const int n = blockIdx.x;
  const int t = threadIdx.x;  // = k
  const float ss = ssq[n * 64 + t];
  const float invk = 1.f / fmaxf(sqrtf(ss), EPSF);
  float r = ss * invk * invk;
#pragma unroll
  for (int off = 32; off >= 1; off >>= 1) r += __shfl_xor(r, off, 64);
  const float ginv = 1.f / fmaxf(sqrtf(r), EPSF);
  scale[n * 64 + t] = invk * ginv;
}

__global__ __launch_bounds__(256) void kC3(float* __restrict__ out,
                                           const float* __restrict__ scale) {
  const int i = blockIdx.x * 256 + threadIdx.x;
  const int row = i / 192;
  const float s = scale[row];
  float4 v = ((float4*)out)[i];
  v.x *= s; v.y *= s; v.z *= s; v.w *= s;
  ((float4*)out)[i] = v;
}

// ---------------------------------------------------------------------------
extern "C" void kernel_launch(void* const* d_in, const int* in_sizes, int n_in,
                              void* d_out, int out_size, void* d_ws, size_t ws_size,
                              hipStream_t stream) {
  const float* x = (const float*)d_in[0];  // [64,768,24,24]
  const float* w = (const float*)d_in[1];  // [64,768]
  float* out = (float*)d_out;              // [64, 64*768]

  u16* attH = (u16*)d_ws;                               // [64,64,576] bf16 hi
  u16* attL = attH + (size_t)64 * 64 * 576;             // lo plane
  float* ssq = (float*)(attL + (size_t)64 * 64 * 576);  // [4096]
  float* scale = ssq + 4096;                            // [4096]

  kA<<<576, 256, 0, stream>>>(x, w, attH, attL);
  kB<<<768, 256, 0, stream>>>(x, attH, attL, out);
  kC1<<<4096, 64, 0, stream>>>(out, ssq);
  kC2<<<64, 64, 0, stream>>>(ssq, scale);
  kC3<<<3072, 256, 0, stream>>>(out, scale);
}

// Round 5
// 79.589 us; speedup vs baseline: 2.0368x; 1.1740x over previous
//
#include <hip/hip_runtime.h>
#include <math.h>

#define EPSF 1e-12f
#define DD 768
#define LL 576

typedef unsigned short u16;
typedef __attribute__((ext_vector_type(8))) short bf16x8;
typedef __attribute__((ext_vector_type(4))) float f32x4;

__device__ __forceinline__ u16 bf16h(float v) {
  unsigned u = __float_as_uint(v);
  return (u16)((u + 0x7FFFu + ((u >> 16) & 1u)) >> 16);
}

// split 8 floats -> packed hi uint4, lo uint4 (bf16 RNE, lo = v - hi)
__device__ __forceinline__ void split8(const float* v, uint4& ph, uint4& pl) {
  unsigned h[8], lo[8];
#pragma unroll
  for (int i = 0; i < 8; ++i) {
    unsigned u = __float_as_uint(v[i]);
    unsigned r = (u + 0x7FFFu + ((u >> 16) & 1u)) >> 16;
    h[i] = r;
    float rest = v[i] - __uint_as_float(r << 16);
    unsigned u2 = __float_as_uint(rest);
    lo[i] = (u2 + 0x7FFFu + ((u2 >> 16) & 1u)) >> 16;
  }
  ph = make_uint4(h[0] | (h[1] << 16), h[2] | (h[3] << 16),
                  h[4] | (h[5] << 16), h[6] | (h[7] << 16));
  pl = make_uint4(lo[0] | (lo[1] << 16), lo[2] | (lo[3] << 16),
                  lo[4] | (lo[5] << 16), lo[6] | (lo[7] << 16));
}

// split 4 floats -> packed hi uint2, lo uint2
__device__ __forceinline__ void split4(const float* v, uint2& ph, uint2& pl) {
  unsigned h[4], lo[4];
#pragma unroll
  for (int i = 0; i < 4; ++i) {
    unsigned u = __float_as_uint(v[i]);
    unsigned r = (u + 0x7FFFu + ((u >> 16) & 1u)) >> 16;
    h[i] = r;
    float rest = v[i] - __uint_as_float(r << 16);
    unsigned u2 = __float_as_uint(rest);
    lo[i] = (u2 + 0x7FFFu + ((u2 >> 16) & 1u)) >> 16;
  }
  ph = make_uint2(h[0] | (h[1] << 16), h[2] | (h[3] << 16));
  pl = make_uint2(lo[0] | (lo[1] << 16), lo[2] | (lo[3] << 16));
}

// Layout probe: D1 = (bcast m-label) x (ones) -> 32*row ; D2 = (ones) x
// (bcast n-label) -> 32*col. True (row,col) per acc reg, any convention.
__device__ __forceinline__ void probe_layout(int lane, int* rowz, int* colz) {
  bf16x8 va, v1;
  const short ml = (short)bf16h((float)(lane & 15));
  const short on = (short)0x3F80;  // bf16(1.0)
#pragma unroll
  for (int e = 0; e < 8; ++e) { va[e] = ml; v1[e] = on; }
  f32x4 z = {0.f, 0.f, 0.f, 0.f};
  f32x4 D1 = __builtin_amdgcn_mfma_f32_16x16x32_bf16(va, v1, z, 0, 0, 0);
  f32x4 D2 = __builtin_amdgcn_mfma_f32_16x16x32_bf16(v1, va, z, 0, 0, 0);
#pragma unroll
  for (int r = 0; r < 4; ++r) {
    rowz[r] = (int)(D1[r] * 0.03125f + 0.5f);
    colz[r] = (int)(D2[r] * 0.03125f + 0.5f);
  }
}

// ---------------------------------------------------------------------------
// kW: pre-split W into bf16 hi/lo A-fragments, fragment-major:
// wf[((strip*24 + s)*64 + lane)*8 + j] = W[strip*16+(lane&15)][s*32+(lane>>4)*8+j]
// ---------------------------------------------------------------------------
__global__ __launch_bounds__(256) void kW(const float* __restrict__ w,
                                          u16* __restrict__ wfH,
                                          u16* __restrict__ wfL) {
  const int s = blockIdx.x;  // 0..23
  const int t = threadIdx.x;
  const int strip = t >> 6, lane = t & 63;
  const int k = strip * 16 + (lane & 15);
  const int d = s * 32 + (lane >> 4) * 8;
  float v[8];
  *(float4*)&v[0] = *(const float4*)(w + k * DD + d);
  *(float4*)&v[4] = *(const float4*)(w + k * DD + d + 4);
  uint4 ph, pl;
  split8(v, ph, pl);
  const size_t o = ((size_t)(strip * 24 + s) * 64 + lane) * 8;
  *(uint4*)(wfH + o) = ph;
  *(uint4*)(wfL + o) = pl;
}

// ---------------------------------------------------------------------------
// kA: per (n, 32-l tile): logits = W @ X via split-bf16 MFMA.
// W from precomputed fragments (global, L2-hot). X reg-prefetched one step
// ahead; LDS transpose+split once per step. Probe-based scatter; softmax.
// ---------------------------------------------------------------------------
__global__ __launch_bounds__(256) void kA(const float* __restrict__ x,
                                          const u16* __restrict__ wfH,
                                          const u16* __restrict__ wfL,
                                          u16* __restrict__ attH,
                                          u16* __restrict__ attL) {
  __shared__ __align__(16) char pool[9728];
  float (*raw)[36] = (float(*)[36])pool;       // [32d][32l+4] fp32
  u16 (*Xh)[40] = (u16(*)[40])(pool + 4608);   // [32l][32d swizzled]+pad
  u16 (*Xl)[40] = (u16(*)[40])(pool + 7168);
  float (*Ls)[36] = (float(*)[36])pool;        // [64k][32l+4] aliases pool
  __shared__ float red8[8][32];
  __shared__ float colinv[32], colmax[32], colscale[32];

  const int b = blockIdx.x;
  const int n = b / 18, l0 = (b % 18) * 32;
  const int t = threadIdx.x;
  const int wv = t >> 6, lane = t & 63;

  int rowz[4], colz[4];
  probe_layout(lane, rowz, colz);

  f32x4 z = {0.f, 0.f, 0.f, 0.f};
  f32x4 acc[2] = {z, z};
  float ssq4[4] = {0.f, 0.f, 0.f, 0.f};

  const int xd = t >> 3;        // 0..31 staging row
  const int xl = (t & 7) * 4;   // staging l quad
  const int tl = lane & 31;     // transpose l
  const int half = lane >> 5;   // transpose d-half

  const float* xbase = x + (size_t)n * DD * LL + l0;
  const u16* wfHp = wfH + ((size_t)wv * 24 * 64 + lane) * 8;
  const u16* wfLp = wfL + ((size_t)wv * 24 * 64 + lane) * 8;

  float4 pre = *(const float4*)(xbase + (size_t)xd * LL + xl);

  for (int s = 0; s < 24; ++s) {
    __syncthreads();  // prev transpose raw-reads + prev MFMA Xh/Xl-reads done
    *(float4*)&raw[xd][xl] = pre;
    ssq4[0] = fmaf(pre.x, pre.x, ssq4[0]);
    ssq4[1] = fmaf(pre.y, pre.y, ssq4[1]);
    ssq4[2] = fmaf(pre.z, pre.z, ssq4[2]);
    ssq4[3] = fmaf(pre.w, pre.w, ssq4[3]);
    if (s < 23)
      pre = *(const float4*)(xbase + (size_t)((s + 1) * 32 + xd) * LL + xl);
    bf16x8 Ah = *(const bf16x8*)(wfHp + (size_t)s * 512);
    bf16x8 Alo = *(const bf16x8*)(wfLp + (size_t)s * 512);
    __syncthreads();  // raw ready
    // transpose+split: thread (dg=wv, half, tl) handles 4 d-elements
    {
      float v[4];
#pragma unroll
      for (int j = 0; j < 4; ++j) v[j] = raw[wv * 8 + half * 4 + j][tl];
      uint2 ph, pl;
      split4(v, ph, pl);
      const int pb = (wv ^ ((tl >> 3) & 3)) * 8 + half * 4;
      *(uint2*)&Xh[tl][pb] = ph;
      *(uint2*)&Xl[tl][pb] = pl;
    }
    __syncthreads();  // Xh/Xl ready
#pragma unroll
    for (int lt = 0; lt < 2; ++lt) {
      const int bl = lt * 16 + (lane & 15);
      const int pb = ((lane >> 4) ^ ((bl >> 3) & 3)) * 8;
      bf16x8 Bh = *(const bf16x8*)&Xh[bl][pb];
      bf16x8 Bl = *(const bf16x8*)&Xl[bl][pb];
      acc[lt] = __builtin_amdgcn_mfma_f32_16x16x32_bf16(Ah, Bh, acc[lt], 0, 0, 0);
      acc[lt] = __builtin_amdgcn_mfma_f32_16x16x32_bf16(Ah, Bl, acc[lt], 0, 0, 0);
      acc[lt] = __builtin_amdgcn_mfma_f32_16x16x32_bf16(Alo, Bh, acc[lt], 0, 0, 0);
    }
  }

  // ssq reduce across xd-within-wave (lane bits 3,4,5); cg = lane&7
#pragma unroll
  for (int i = 0; i < 4; ++i) {
    ssq4[i] += __shfl_xor(ssq4[i], 8, 64);
    ssq4[i] += __shfl_xor(ssq4[i], 16, 64);
    ssq4[i] += __shfl_xor(ssq4[i], 32, 64);
  }
  if (lane < 8) {
#pragma unroll
    for (int i = 0; i < 4; ++i) red8[wv][lane * 4 + i] = ssq4[i];
  }
  __syncthreads();  // also guards Ls scatter vs last MFMA reads
  if (t < 32)
    colinv[t] =
        1.f / fmaxf(sqrtf(red8[0][t] + red8[1][t] + red8[2][t] + red8[3][t]), EPSF);
  // scatter raw logits using PROBED positions (Ls aliases dead staging pool)
#pragma unroll
  for (int lt = 0; lt < 2; ++lt)
#pragma unroll
    for (int r = 0; r < 4; ++r)
      Ls[wv * 16 + rowz[r]][lt * 16 + colz[r]] = acc[lt][r];
  __syncthreads();

  // softmax over k per column; thread (q=t>>5, cl=t&31) owns 8 k's
  const int cl = t & 31, q = t >> 5;
  const float cinv = colinv[cl];
  float sv[8];
  float m = -1e30f;
#pragma unroll
  for (int i = 0; i < 8; ++i) {
    const float vv = Ls[q * 8 + i][cl] * cinv;
    sv[i] = vv;
    m = fmaxf(m, vv);
  }
  red8[q][cl] = m;
  __syncthreads();
  if (t < 32) {
    float mm = red8[0][t];
#pragma unroll
    for (int j = 1; j < 8; ++j) mm = fmaxf(mm, red8[j][t]);
    colmax[t] = mm;
  }
  __syncthreads();
  const float M = colmax[cl];
  float ssum = 0.f;
#pragma unroll
  for (int i = 0; i < 8; ++i) {
    const float e = expf(sv[i] - M);
    sv[i] = e;
    ssum += e;
  }
  red8[q][cl] = ssum;
  __syncthreads();
  if (t < 32) {
    float ss = red8[0][t];
#pragma unroll
    for (int j = 1; j < 8; ++j) ss += red8[j][t];
    colscale[t] = colinv[t] / ss;
  }
  __syncthreads();
  const float cs = colscale[cl];
  u16* aH = attH + (size_t)n * 64 * LL + l0 + cl;
  u16* aL = attL + (size_t)n * 64 * LL + l0 + cl;
#pragma unroll
  for (int i = 0; i < 8; ++i) {
    const int k = q * 8 + i;
    const float e = sv[i] * cs;
    unsigned u = __float_as_uint(e);
    unsigned r = (u + 0x7FFFu + ((u >> 16) & 1u)) >> 16;
    const float rest = e - __uint_as_float(r << 16);
    aH[(size_t)k * LL] = (u16)r;
    aL[(size_t)k * LL] = bf16h(rest);
  }
}

// ---------------------------------------------------------------------------
// kB: per (n, 64-d tile): out[k][d] = sum_l att'[k][l] * x[d][l], split-bf16
// MFMA, reg-prefetched staging. Output positions from probe.
// ---------------------------------------------------------------------------
__global__ __launch_bounds__(256) void kB(const float* __restrict__ x,
                                          const u16* __restrict__ attH,
                                          const u16* __restrict__ attL,
                                          float* __restrict__ out) {
  __shared__ __align__(16) u16 AH[64][40];
  __shared__ __align__(16) u16 AL[64][40];
  __shared__ __align__(16) u16 Xh[64][40];
  __shared__ __align__(16) u16 Xl[64][40];
  const int b = blockIdx.x;
  const int n = b / 12, d0 = (b % 12) * 64;
  const int t = threadIdx.x;
  const int wv = t >> 6, lane = t & 63;

  int rowz[4], colz[4];
  probe_layout(lane, rowz, colz);

  f32x4 z = {0.f, 0.f, 0.f, 0.f};
  f32x4 acc[4] = {z, z, z, z};

  const int rk = t >> 2;       // staging row 0..63
  const int lb = (t & 3) * 8;  // l offset 0,8,16,24

  const u16* aHb = attH + ((size_t)n * 64 + rk) * LL + lb;
  const u16* aLb = attL + ((size_t)n * 64 + rk) * LL + lb;
  const float* xb = x + ((size_t)n * DD + d0 + rk) * LL + lb;

  uint4 pAH = *(const uint4*)aHb;
  uint4 pAL = *(const uint4*)aLb;
  float4 pX0 = *(const float4*)xb;
  float4 pX1 = *(const float4*)(xb + 4);

  for (int s = 0; s < 18; ++s) {
    __syncthreads();  // prev MFMA reads done
    *(uint4*)&AH[rk][lb] = pAH;
    *(uint4*)&AL[rk][lb] = pAL;
    {
      float v[8] = {pX0.x, pX0.y, pX0.z, pX0.w, pX1.x, pX1.y, pX1.z, pX1.w};
      uint4 ph, pl;
      split8(v, ph, pl);
      *(uint4*)&Xh[rk][lb] = ph;
      *(uint4*)&Xl[rk][lb] = pl;
    }
    if (s < 17) {
      const int lo = (s + 1) * 32;
      pAH = *(const uint4*)(aHb + lo);
      pAL = *(const uint4*)(aLb + lo);
      pX0 = *(const float4*)(xb + lo);
      pX1 = *(const float4*)(xb + lo + 4);
    }
    __syncthreads();  // staged
    const int ar = wv * 16 + (lane & 15);
    const int ab = (lane >> 4) * 8;
    bf16x8 Ah = *(const bf16x8*)&AH[ar][ab];
    bf16x8 Alo = *(const bf16x8*)&AL[ar][ab];
#pragma unroll
    for (int dt = 0; dt < 4; ++dt) {
      const int br = dt * 16 + (lane & 15);
      bf16x8 Bh = *(const bf16x8*)&Xh[br][ab];
      bf16x8 Bl = *(const bf16x8*)&Xl[br][ab];
      acc[dt] = __builtin_amdgcn_mfma_f32_16x16x32_bf16(Ah, Bh, acc[dt], 0, 0, 0);
      acc[dt] = __builtin_amdgcn_mfma_f32_16x16x32_bf16(Ah, Bl, acc[dt], 0, 0, 0);
      acc[dt] = __builtin_amdgcn_mfma_f32_16x16x32_bf16(Alo, Bh, acc[dt], 0, 0, 0);
    }
  }

  // store raw out using PROBED positions
  float* ob = out + ((size_t)n * 64 + wv * 16) * DD + d0;
#pragma unroll
  for (int dt = 0; dt < 4; ++dt)
#pragma unroll
    for (int r = 0; r < 4; ++r)
      ob[(size_t)rowz[r] * DD + dt * 16 + colz[r]] = acc[dt][r];
}

// ---------------------------------------------------------------------------
// Epilogue
// ---------------------------------------------------------------------------
__global__ __launch_bounds__(64) void kC1(const float* __restrict__ out,
                                          float* __restrict__ ssq) {
  const int b = blockIdx.x;  // n*64 + k
  const int t = threadIdx.x;
  const float* p = out + (size_t)b * DD;
  float s = 0.f;
#pragma unroll
  for (int i = 0; i < 12; ++i) {
    const float v = p[t + 64 * i];
    s = fmaf(v, v, s);
  }
#pragma unroll
  for (int off = 32; off >= 1; off >>= 1) s += __shfl_xor(s, off, 64);
  if (t == 0) ssq[b] = s;
}

__global__ __launch_bounds__(64) void kC2(const float* __restrict__ ssq,
                                          float* __restrict__ scale) {
  const int n = blockIdx.x;
  const int t = threadIdx.x;  // = k
  const float ss = ssq[n * 64 + t];
  const float invk = 1.f / fmaxf(sqrtf(ss), EPSF);
  float r = ss * invk * invk;
#pragma unroll
  for (int off = 32; off >= 1; off >>= 1) r += __shfl_xor(r, off, 64);
  const float ginv = 1.f / fmaxf(sqrtf(r), EPSF);
  scale[n * 64 + t] = invk * ginv;
}

__global__ __launch_bounds__(256) void kC3(float* __restrict__ out,
                                           const float* __restrict__ scale) {
  const int i = blockIdx.x * 256 + threadIdx.x;
  const int row = i / 192;
  const float s = scale[row];
  float4 v = ((float4*)out)[i];
  v.x *= s; v.y *= s; v.z *= s; v.w *= s;
  ((float4*)out)[i] = v;
}

// ---------------------------------------------------------------------------
extern "C" void kernel_launch(void* const* d_in, const int* in_sizes, int n_in,
                              void* d_out, int out_size, void* d_ws, size_t ws_size,
                              hipStream_t stream) {
  const float* x = (const float*)d_in[0];  // [64,768,24,24]
  const float* w = (const float*)d_in[1];  // [64,768]
  float* out = (float*)d_out;              // [64, 64*768]

  u16* attH = (u16*)d_ws;                    // [64,64,576] bf16 hi
  u16* attL = attH + (size_t)2359296;        // lo plane
  u16* wfH = attL + (size_t)2359296;         // W fragments hi [4*24*64*8]
  u16* wfL = wfH + 49152;                    // W fragments lo
  float* ssq = (float*)(wfL + 49152);        // [4096]
  float* scale = ssq + 4096;                 // [4096]

  kW<<<24, 256, 0, stream>>>(w, wfH, wfL);
  kA<<<1152, 256, 0, stream>>>(x, wfH, wfL, attH, attL);
  kB<<<768, 256, 0, stream>>>(x, attH, attL, out);
  kC1<<<4096, 64, 0, stream>>>(out, ssq);
  kC2<<<64, 64, 0, stream>>>(ssq, scale);
  kC3<<<3072, 256, 0, stream>>>(out, scale);
}